// Round 21
// baseline (295.881 us; speedup 1.0000x reference)
//
#include <hip/hip_runtime.h>
#include <hip/hip_bf16.h>
#include <cmath>

typedef unsigned short u16;
typedef unsigned int u32;

using bf16x8 = __attribute__((ext_vector_type(8))) short;
using f32x4  = __attribute__((ext_vector_type(4))) float;

__device__ __forceinline__ float b2f(u16 u) {
  union { u32 i; float f; } x; x.i = ((u32)u) << 16; return x.f;
}
__device__ __forceinline__ u16 f2b(float f) {
  union { float f; u32 i; } x; x.f = f;
  u32 r = x.i + 0x7fffu + ((x.i >> 16) & 1u);
  return (u16)(r >> 16);
}
__device__ __forceinline__ u32 cvtpk(float lo, float hi) {
  u32 r;
  asm("v_cvt_pk_bf16_f32 %0, %1, %2" : "=v"(r) : "v"(lo), "v"(hi));
  return r;
}
__device__ __forceinline__ float vexp2(float x) {
  float r;
  asm("v_exp_f32 %0, %1" : "=v"(r) : "v"(x));
  return r;
}
__device__ __forceinline__ float vmax3(float a, float b, float c) {
  float r;
  asm("v_max3_f32 %0, %1, %2, %3" : "=v"(r) : "v"(a), "v"(b), "v"(c));
  return r;
}
__device__ __forceinline__ void gload_lds16(const u16* g, u16* l) {
  __builtin_amdgcn_global_load_lds(
      (const __attribute__((address_space(1))) unsigned int*)g,
      (__attribute__((address_space(3))) unsigned int*)l, 16, 0, 0);
}

// ---------------- fused preamble: LN1(+gather) | bias table | weight cast --
__global__ __launch_bounds__(256) void pre_k(
    const float* __restrict__ x, const float* __restrict__ n1g,
    const float* __restrict__ n1b, const float* __restrict__ qkvw,
    const float* __restrict__ projw, const float* __restrict__ fc1w,
    const float* __restrict__ fc2w, const float* __restrict__ rpb,
    u16* __restrict__ xw, u16* __restrict__ wts, u16* __restrict__ biasB) {
  const int blk = blockIdx.x;
  const int tid = threadIdx.x;
  if (blk < 12544) {
    const int wid = tid >> 6, lane = tid & 63;
    const int row = blk * 4 + wid;
    int widx = row / 392, n = row - widx * 392;
    int wt = widx >> 6, wh = (widx >> 3) & 7, ww = widx & 7;
    int ti = n / 49, rem = n - ti * 49, hi = rem / 7, wi = rem - hi * 7;
    int t = (wt * 8 + ti + 4) & 15;
    int h = wh * 7 + hi + 3; if (h >= 56) h -= 56;
    int w = ww * 7 + wi + 3; if (w >= 56) w -= 56;
    int srow = (t * 56 + h) * 56 + w;
    float4 v = *(const float4*)(x + (size_t)srow * 256 + lane * 4);
    float s = v.x + v.y + v.z + v.w;
    float sq = v.x * v.x + v.y * v.y + v.z * v.z + v.w * v.w;
    for (int o = 1; o < 64; o <<= 1) {
      s += __shfl_xor(s, o, 64);
      sq += __shfl_xor(sq, o, 64);
    }
    float mu = s * (1.0f / 256.0f);
    float rstd = rsqrtf(sq * (1.0f / 256.0f) - mu * mu + 1e-5f);
    float4 gg = *(const float4*)(n1g + lane * 4);
    float4 bb = *(const float4*)(n1b + lane * 4);
    ushort4 ov;
    ov.x = f2b((v.x - mu) * rstd * gg.x + bb.x);
    ov.y = f2b((v.y - mu) * rstd * gg.y + bb.y);
    ov.z = f2b((v.z - mu) * rstd * gg.z + bb.z);
    ov.w = f2b((v.w - mu) * rstd * gg.w + bb.w);
    *(ushort4*)(xw + (size_t)row * 256 + lane * 4) = ov;
  } else if (blk < 14144) {
    const int b = blk - 12544;  // sl*25 + qt
    const int sl = b / 25, qt = b - sl * 25;
    const int head = sl & 7, cls = sl >> 3;
    const int tb = (cls >> 2) & 1, hb = (cls >> 1) & 1, wb = cls & 1;
    const int lm = tid >> 4, kl = tid & 15;
    int q = qt * 16 + lm; if (q > 391) q = 391;
    const int ti = q / 49, rem = q - ti * 49, hi = rem / 7, wi = rem - hi * 7;
    const int cq = ti * 169 + hi * 13 + wi;
    const int rtq = tb ? (ti < 4 ? 1 : 2) : 0;
    const int rhq = hb ? (hi < 4 ? 1 : 2) : 0;
    const int rwq = wb ? (wi < 4 ? 1 : 2) : 0;
    const int labq = rtq * 9 + rhq * 3 + rwq;
    u16* ob = biasB + (size_t)b * 6400 + tid;
    for (int t = 0; t < 25; t++) {
      int k = t * 16 + kl;
      float v;
      if (k < 392) {
        int tk = k / 49, rk = k - tk * 49, hk = rk / 7, wk = rk - hk * 7;
        int ck = tk * 169 + hk * 13 + wk;
        float bv = rpb[(cq - ck + 1267) * 8 + head];
        int rt = tb ? (tk < 4 ? 1 : 2) : 0;
        int rh = hb ? (hk < 4 ? 1 : 2) : 0;
        int rw = wb ? (wk < 4 ? 1 : 2) : 0;
        if (rt * 9 + rh * 3 + rw != labq) bv -= 100.f;
        v = bv * 1.4426950408889634f;
      } else {
        v = -2081.f;  // pad keys: exp2 -> exactly 0
      }
      ob[t * 256] = f2b(v);
    }
  } else {
    int i = (blk - 14144) * 256 + tid;  // < 786432
    const float* src;
    int off;
    if (i < 196608)      { src = qkvw;  off = 0; }
    else if (i < 262144) { src = projw; off = 196608; }
    else if (i < 524288) { src = fc1w;  off = 262144; }
    else                 { src = fc2w;  off = 524288; }
    wts[i] = f2b(src[i - off]);
  }
}

// ---------------- LayerNorm (no gather), for LN2 --------------------------
__global__ __launch_bounds__(256) void ln_k(const float* __restrict__ src,
                                            const float* __restrict__ g,
                                            const float* __restrict__ b,
                                            u16* __restrict__ dst) {
  const int wid = threadIdx.x >> 6, lane = threadIdx.x & 63;
  const int row = blockIdx.x * 4 + wid;
  float4 v = *(const float4*)(src + (size_t)row * 256 + lane * 4);
  float s = v.x + v.y + v.z + v.w;
  float sq = v.x * v.x + v.y * v.y + v.z * v.z + v.w * v.w;
  for (int o = 1; o < 64; o <<= 1) {
    s += __shfl_xor(s, o, 64);
    sq += __shfl_xor(sq, o, 64);
  }
  float mu = s * (1.0f / 256.0f);
  float rstd = rsqrtf(sq * (1.0f / 256.0f) - mu * mu + 1e-5f);
  float4 gg = *(const float4*)(g + lane * 4);
  float4 bb = *(const float4*)(b + lane * 4);
  ushort4 ov;
  ov.x = f2b((v.x - mu) * rstd * gg.x + bb.x);
  ov.y = f2b((v.y - mu) * rstd * gg.y + bb.y);
  ov.z = f2b((v.z - mu) * rstd * gg.z + bb.z);
  ov.w = f2b((v.w - mu) * rstd * gg.w + bb.w);
  *(ushort4*)(dst + (size_t)row * 256 + lane * 4) = ov;
}

// ---------------- MFMA GEMM: C = A(MxK) @ B(NxK)^T -----------------------
template <int EPI>
__global__ __launch_bounds__(512) void gemm_k(const u16* __restrict__ A,
                                              const u16* __restrict__ Bw,
                                              int K, int tilesN,
                                              const float* __restrict__ bias,
                                              u16* __restrict__ outb,
                                              float* __restrict__ outf,
                                              const float* __restrict__ res,
                                              float qscale) {
  __shared__ __align__(16) u16 As[2][256 * 32];
  __shared__ __align__(16) u16 Bs[2][128 * 32];
  const int tid = threadIdx.x;
  const int swzb = ((int)blockIdx.x & 7) * ((int)gridDim.x >> 3) +
                   ((int)blockIdx.x >> 3);
  const int tm = swzb / tilesN, tn = swzb - tm * tilesN;
  const int wid = tid >> 6, lane = tid & 63;
  const int wm = wid >> 1, wn = wid & 1;
  const int lm = lane & 15, lk = lane >> 4;
  f32x4 acc[4][4] = {};
  const u16* Ap = A + (size_t)tm * 256 * K;
  const u16* Bp = Bw + (size_t)tn * 128 * K;

  const int sA0 = wid * 128;
  const int sB0 = wid * 64;
  const int nt = K >> 5;

#define STAGE(bufi, kk)                                                       \
  {                                                                           \
    int S = sA0 + lane, r = S >> 2, cs = S & 3;                               \
    gload_lds16(Ap + (size_t)r * K + (kk) + ((cs ^ ((r >> 1) & 3)) << 3),     \
                &As[bufi][sA0 * 8]);                                          \
    S = sA0 + 64 + lane; r = S >> 2; cs = S & 3;                              \
    gload_lds16(Ap + (size_t)r * K + (kk) + ((cs ^ ((r >> 1) & 3)) << 3),     \
                &As[bufi][(sA0 + 64) * 8]);                                   \
    S = sB0 + lane; r = S >> 2; cs = S & 3;                                   \
    gload_lds16(Bp + (size_t)r * K + (kk) + ((cs ^ ((r >> 1) & 3)) << 3),     \
                &Bs[bufi][sB0 * 8]);                                          \
  }

  STAGE(0, 0);
  for (int t = 0; t < nt; t++) {
    const int cur = t & 1;
    if (t + 1 < nt) {
      STAGE(cur ^ 1, (t + 1) << 5);
      asm volatile("s_waitcnt vmcnt(3)" ::: "memory");
    } else {
      asm volatile("s_waitcnt vmcnt(0)" ::: "memory");
    }
    asm volatile("s_barrier" ::: "memory");
    __builtin_amdgcn_sched_barrier(0);
    bf16x8 af[4], bfr[4];
#pragma unroll
    for (int f = 0; f < 4; f++) {
      int ra = wm * 64 + f * 16 + lm;
      int rb = wn * 64 + f * 16 + lm;
      af[f] = *(const bf16x8*)((const char*)&As[cur][0] + ra * 64 +
                               ((lk ^ ((ra >> 1) & 3)) << 4));
      bfr[f] = *(const bf16x8*)((const char*)&Bs[cur][0] + rb * 64 +
                                ((lk ^ ((rb >> 1) & 3)) << 4));
    }
#pragma unroll
    for (int fm = 0; fm < 4; fm++)
#pragma unroll
      for (int fn = 0; fn < 4; fn++)
        acc[fm][fn] = __builtin_amdgcn_mfma_f32_16x16x32_bf16(
            af[fm], bfr[fn], acc[fm][fn], 0, 0, 0);
    asm volatile("s_barrier" ::: "memory");
  }
#undef STAGE

  const int rbase = tm * 256 + wm * 64, cbase = tn * 128 + wn * 64;
#pragma unroll
  for (int fm = 0; fm < 4; fm++) {
#pragma unroll
    for (int fn = 0; fn < 4; fn++) {
      const int col = cbase + fn * 16 + lm;
#pragma unroll
      for (int r = 0; r < 4; r++) {
        const int row = rbase + fm * 16 + lk * 4 + r;
        float v = acc[fm][fn][r] + bias[col];
        if (EPI == 0) {
          int s = col >> 8, rem = col & 255, head = rem >> 5, d = rem & 31;
          int widx = row / 392, n = row - widx * 392;
          size_t o;
          if (s == 2) {
            int c = n >> 5, gg2 = (n >> 3) & 3, e = n & 7;
            int lm2 = d & 15, half = d >> 4;
            o = 25690112u + (size_t)(widx * 8 + head) * 13312 +
                (size_t)(((c * 2 + half) * 64) + gg2 * 16 + lm2) * 8 + e;
          } else {
            if (s == 0) v *= qscale;
            o = (size_t)s * 12845056u +
                (((size_t)(widx * 8 + head)) * 392 + n) * 32 + d;
          }
          outb[o] = f2b(v);
        } else if (EPI == 1) {
          int widx = row / 392, n = row - widx * 392;
          int wt = widx >> 6, wh = (widx >> 3) & 7, ww = widx & 7;
          int ti = n / 49, rem2 = n - ti * 49, hi = rem2 / 7, wi = rem2 - hi * 7;
          int t = (wt * 8 + ti + 4) & 15;
          int h = wh * 7 + hi + 3; if (h >= 56) h -= 56;
          int w = ww * 7 + wi + 3; if (w >= 56) w -= 56;
          size_t dr = ((size_t)(t * 56 + h)) * 56 + w;
          outf[dr * 256 + col] = res[dr * 256 + col] + v;
        } else if (EPI == 2) {
          float gv = 0.5f * v * (1.0f + erff(v * 0.70710678f));
          outb[(size_t)row * 1024 + col] = f2b(gv);
        } else {
          outf[(size_t)row * 256 + col] = res[(size_t)row * 256 + col] + v;
        }
      }
    }
  }
}

// ---------------- MFMA windowed attention (r18 + T5 setprio + T17 max3) ---
__global__ __launch_bounds__(256) void attn_k(const u16* __restrict__ qg,
                                              const u16* __restrict__ kg,
                                              const u16* __restrict__ vfg,
                                              const u16* __restrict__ biasB,
                                              u16* __restrict__ attno) {
  __shared__ __align__(16) char lds[59904];
  const int bid = blockIdx.x;  // widx*8 + head
  const int widx = bid >> 3;
  const int tid = threadIdx.x;
  const size_t base = (size_t)bid * 12544;
  const int tb = (widx >> 6) & 1;
  const int hb = (((widx >> 3) & 7) == 7) ? 1 : 0;
  const int wb = ((widx & 7) == 7) ? 1 : 0;
  const int sl = (tb * 4 + hb * 2 + wb) * 8 + (bid & 7);
  const int VOFF = 25088;
  const int POFF = 51712;

#pragma unroll
  for (int i = 0; i < 6; i++) {
    int s = i * 256 + tid, r = s >> 2, cs = s & 3;
    gload_lds16(kg + base + r * 32 + ((cs ^ ((r >> 1) & 3)) << 3),
                (u16*)(lds + (size_t)(i * 256 + (tid & ~63)) * 16));
  }
  if (tid < 32) {
    int s = 1536 + tid, r = s >> 2, cs = s & 3;
    gload_lds16(kg + base + r * 32 + ((cs ^ ((r >> 1) & 3)) << 3),
                (u16*)(lds + (size_t)1536 * 16));
  }
  {
    const u16* vsrc = vfg + (size_t)bid * 13312;
#pragma unroll
    for (int i = 0; i < 6; i++) {
      int s = i * 256 + tid;
      gload_lds16(vsrc + (size_t)s * 8,
                  (u16*)(lds + VOFF + (size_t)(i * 256 + (tid & ~63)) * 16));
    }
    if (tid < 128) {
      int s = 1536 + tid;
      gload_lds16(vsrc + (size_t)s * 8,
                  (u16*)(lds + VOFF + (size_t)(1536 + (tid & ~63)) * 16));
    }
  }
  __syncthreads();

  const int w = tid >> 6, lane = tid & 63;
  const int g = lane >> 4, lm = lane & 15;
  const int kswz = ((lm >> 1) & 3);
  char* PqW = lds + POFF + w * 2048 + lm * 128;
  const int swz = (lm & 7) << 4;
  const char* vlds = lds + VOFF + lane * 16;

  for (int qt = w; qt < 25; qt += 4) {
    const int q = qt * 16 + lm;
    const int qr = q < 391 ? q : 391;
    bf16x8 qf = *(const bf16x8*)(qg + base + (size_t)qr * 32 + g * 8);
    const u16* bp = biasB + ((size_t)(sl * 25 + qt) * 25) * 256 + lm * 16 + 4 * g;
    f32x4 st[25];
    __builtin_amdgcn_s_setprio(1);  // T5: favor the QK^T MFMA cluster
#pragma unroll
    for (int t = 0; t < 25; t++) {
      ushort4 bb = *(const ushort4*)(bp + t * 256);
      f32x4 bacc = {b2f(bb.x), b2f(bb.y), b2f(bb.z), b2f(bb.w)};
      int kr = (t < 24) ? (16 * t + lm) : (384 + (lm & 7));
      bf16x8 kf = *(const bf16x8*)(lds + kr * 64 + ((g ^ kswz) << 4));
      st[t] = __builtin_amdgcn_mfma_f32_16x16x32_bf16(kf, qf, bacc, 0, 0, 0);
    }
    __builtin_amdgcn_s_setprio(0);
    // T17: v_max3 tree over 100 values (2 max3 per tile)
    float m = -3e38f;
#pragma unroll
    for (int t = 0; t < 25; t++) {
      float tm3 = vmax3(st[t][0], st[t][1], st[t][2]);
      m = vmax3(m, tm3, st[t][3]);
    }
    m = fmaxf(m, __shfl_xor(m, 16, 64));
    m = fmaxf(m, __shfl_xor(m, 32, 64));

    float sum = 0.f;
    f32x4 oa0 = {0.f, 0.f, 0.f, 0.f}, oa1 = {0.f, 0.f, 0.f, 0.f};
#pragma unroll
    for (int c = 0; c < 13; c++) {
      const int p64 = (c & 1) << 6;
      {
        int t = 2 * c;
        float e0 = vexp2(st[t][0] - m), e1 = vexp2(st[t][1] - m);
        float e2 = vexp2(st[t][2] - m), e3 = vexp2(st[t][3] - m);
        sum += (e0 + e1) + (e2 + e3);
        uint2 pp;
        pp.x = cvtpk(e0, e1);
        pp.y = cvtpk(e2, e3);
        *(uint2*)(PqW + ((p64 + 8 * g) ^ swz)) = pp;
      }
      {
        uint2 pp;
        if (c < 12) {
          int t = 2 * c + 1;
          float e0 = vexp2(st[t][0] - m), e1 = vexp2(st[t][1] - m);
          float e2 = vexp2(st[t][2] - m), e3 = vexp2(st[t][3] - m);
          sum += (e0 + e1) + (e2 + e3);
          pp.x = cvtpk(e0, e1);
          pp.y = cvtpk(e2, e3);
        } else {
          pp.x = 0u; pp.y = 0u;
        }
        *(uint2*)(PqW + ((p64 + 32 + 8 * g) ^ swz)) = pp;
      }
      bf16x8 pf = *(const bf16x8*)(PqW + ((p64 + 16 * g) ^ swz));
      const char* vp = vlds + c * 2048;
      bf16x8 v0 = *(const bf16x8*)vp;
      bf16x8 v1 = *(const bf16x8*)(vp + 1024);
      __builtin_amdgcn_s_setprio(1);  // T5: favor the PV MFMA pair
      oa0 = __builtin_amdgcn_mfma_f32_16x16x32_bf16(pf, v0, oa0, 0, 0, 0);
      oa1 = __builtin_amdgcn_mfma_f32_16x16x32_bf16(pf, v1, oa1, 0, 0, 0);
      __builtin_amdgcn_s_setprio(0);
    }
    sum += __shfl_xor(sum, 16, 64);
    sum += __shfl_xor(sum, 32, 64);
    const float inv = 1.f / sum;
#pragma unroll
    for (int r = 0; r < 4; r++) {
      int qq = qt * 16 + 4 * g + r;
      if (qq < 392) {
        u16* op = attno + ((size_t)(widx * 392 + qq)) * 256 + (bid & 7) * 32;
        op[lm] = f2b(oa0[r] * inv);
        op[16 + lm] = f2b(oa1[r] * inv);
      }
    }
  }
}

extern "C" void kernel_launch(void* const* d_in, const int* in_sizes, int n_in,
                              void* d_out, int out_size, void* d_ws,
                              size_t ws_size, hipStream_t stream) {
  const float* x     = (const float*)d_in[0];
  const float* n1g   = (const float*)d_in[1];
  const float* n1b   = (const float*)d_in[2];
  const float* qkvw  = (const float*)d_in[3];
  const float* qkvb  = (const float*)d_in[4];
  const float* rpb   = (const float*)d_in[5];
  const float* projw = (const float*)d_in[6];
  const float* projb = (const float*)d_in[7];
  const float* n2g   = (const float*)d_in[8];
  const float* n2b   = (const float*)d_in[9];
  const float* fc1w  = (const float*)d_in[10];
  const float* fc1b  = (const float*)d_in[11];
  const float* fc2w  = (const float*)d_in[12];
  const float* fc2b  = (const float*)d_in[13];

  // Workspace (NEED = 130,547,712 B), lifetime-aliased (round-18 layout):
  //  [0, 25.69M)            xw -> attno -> h2
  //  [25.69M, 77.07M)       q,k           -> hid (low)
  //  [77.07M, 104.33M)      vfrag (27.3M) -> hid (high)
  //  [104.33M, 124.81M)     biasB         -> hid (high)
  //  hid = [25.69M, 128.45M)
  //  [128.97M, 130.55M)     bf16 weights (wq|wp|w1|w2 contiguous)
  // xres (fp32 residual) lives in d_out.
  const size_t NEED = 130547712;
  if (ws_size < NEED) return;

  char* ws = (char*)d_ws;
  u16* xw      = (u16*)(ws + 0LL);
  u16* qb      = (u16*)(ws + 25690112LL);
  u16* attno   = (u16*)(ws + 0LL);
  u16* h2      = (u16*)(ws + 0LL);
  u16* hid     = (u16*)(ws + 25690112LL);
  u16* biasB   = (u16*)(ws + 104333312LL);
  u16* wq      = (u16*)(ws + 128974848LL);
  u16* wp      = (u16*)(ws + 129368064LL);
  u16* w1      = (u16*)(ws + 129499136LL);
  u16* w2      = (u16*)(ws + 130023424LL);
  float* xres  = (float*)d_out;

  pre_k<<<17216, 256, 0, stream>>>(x, n1g, n1b, qkvw, projw, fc1w, fc2w, rpb,
                                   xw, wq, biasB);
  gemm_k<0><<<196 * 6, 512, 0, stream>>>(
      xw, wq, 256, 6, qkvb, qb, nullptr, nullptr,
      0.17677669529663687f * 1.4426950408889634f);
  attn_k<<<1024, 256, 0, stream>>>(qb, qb + 12845056, qb + 2 * 12845056, biasB,
                                   attno);
  gemm_k<1><<<196 * 2, 512, 0, stream>>>(attno, wp, 256, 2, projb, nullptr,
                                         xres, x, 0.f);
  ln_k<<<12544, 256, 0, stream>>>(xres, n2g, n2b, h2);
  gemm_k<2><<<196 * 8, 512, 0, stream>>>(h2, w1, 256, 8, fc1b, hid, nullptr,
                                         nullptr, 0.f);
  gemm_k<3><<<196 * 2, 512, 0, stream>>>(hid, w2, 1024, 2, fc2b, nullptr,
                                         (float*)d_out, xres, 0.f);
}

// Round 22
// 291.608 us; speedup vs baseline: 1.0147x; 1.0147x over previous
//
#include <hip/hip_runtime.h>
#include <hip/hip_bf16.h>
#include <cmath>

typedef unsigned short u16;
typedef unsigned int u32;

using bf16x8 = __attribute__((ext_vector_type(8))) short;
using f32x4  = __attribute__((ext_vector_type(4))) float;

__device__ __forceinline__ float b2f(u16 u) {
  union { u32 i; float f; } x; x.i = ((u32)u) << 16; return x.f;
}
__device__ __forceinline__ u16 f2b(float f) {
  union { float f; u32 i; } x; x.f = f;
  u32 r = x.i + 0x7fffu + ((x.i >> 16) & 1u);
  return (u16)(r >> 16);
}
__device__ __forceinline__ u32 cvtpk(float lo, float hi) {
  u32 r;
  asm("v_cvt_pk_bf16_f32 %0, %1, %2" : "=v"(r) : "v"(lo), "v"(hi));
  return r;
}
__device__ __forceinline__ float vexp2(float x) {
  float r;
  asm("v_exp_f32 %0, %1" : "=v"(r) : "v"(x));
  return r;
}
__device__ __forceinline__ void gload_lds16(const u16* g, u16* l) {
  __builtin_amdgcn_global_load_lds(
      (const __attribute__((address_space(1))) unsigned int*)g,
      (__attribute__((address_space(3))) unsigned int*)l, 16, 0, 0);
}

// ---------------- fused preamble: LN1(+gather) | bias table | weight cast --
__global__ __launch_bounds__(256) void pre_k(
    const float* __restrict__ x, const float* __restrict__ n1g,
    const float* __restrict__ n1b, const float* __restrict__ qkvw,
    const float* __restrict__ projw, const float* __restrict__ fc1w,
    const float* __restrict__ fc2w, const float* __restrict__ rpb,
    u16* __restrict__ xw, u16* __restrict__ wts, u16* __restrict__ biasB) {
  const int blk = blockIdx.x;
  const int tid = threadIdx.x;
  if (blk < 12544) {
    const int wid = tid >> 6, lane = tid & 63;
    const int row = blk * 4 + wid;
    int widx = row / 392, n = row - widx * 392;
    int wt = widx >> 6, wh = (widx >> 3) & 7, ww = widx & 7;
    int ti = n / 49, rem = n - ti * 49, hi = rem / 7, wi = rem - hi * 7;
    int t = (wt * 8 + ti + 4) & 15;
    int h = wh * 7 + hi + 3; if (h >= 56) h -= 56;
    int w = ww * 7 + wi + 3; if (w >= 56) w -= 56;
    int srow = (t * 56 + h) * 56 + w;
    float4 v = *(const float4*)(x + (size_t)srow * 256 + lane * 4);
    float s = v.x + v.y + v.z + v.w;
    float sq = v.x * v.x + v.y * v.y + v.z * v.z + v.w * v.w;
    for (int o = 1; o < 64; o <<= 1) {
      s += __shfl_xor(s, o, 64);
      sq += __shfl_xor(sq, o, 64);
    }
    float mu = s * (1.0f / 256.0f);
    float rstd = rsqrtf(sq * (1.0f / 256.0f) - mu * mu + 1e-5f);
    float4 gg = *(const float4*)(n1g + lane * 4);
    float4 bb = *(const float4*)(n1b + lane * 4);
    ushort4 ov;
    ov.x = f2b((v.x - mu) * rstd * gg.x + bb.x);
    ov.y = f2b((v.y - mu) * rstd * gg.y + bb.y);
    ov.z = f2b((v.z - mu) * rstd * gg.z + bb.z);
    ov.w = f2b((v.w - mu) * rstd * gg.w + bb.w);
    *(ushort4*)(xw + (size_t)row * 256 + lane * 4) = ov;
  } else if (blk < 14144) {
    const int b = blk - 12544;  // sl*25 + qt
    const int sl = b / 25, qt = b - sl * 25;
    const int head = sl & 7, cls = sl >> 3;
    const int tb = (cls >> 2) & 1, hb = (cls >> 1) & 1, wb = cls & 1;
    const int lm = tid >> 4, kl = tid & 15;
    int q = qt * 16 + lm; if (q > 391) q = 391;
    const int ti = q / 49, rem = q - ti * 49, hi = rem / 7, wi = rem - hi * 7;
    const int cq = ti * 169 + hi * 13 + wi;
    const int rtq = tb ? (ti < 4 ? 1 : 2) : 0;
    const int rhq = hb ? (hi < 4 ? 1 : 2) : 0;
    const int rwq = wb ? (wi < 4 ? 1 : 2) : 0;
    const int labq = rtq * 9 + rhq * 3 + rwq;
    u16* ob = biasB + (size_t)b * 6400 + tid;
    for (int t = 0; t < 25; t++) {
      int k = t * 16 + kl;
      float v;
      if (k < 392) {
        int tk = k / 49, rk = k - tk * 49, hk = rk / 7, wk = rk - hk * 7;
        int ck = tk * 169 + hk * 13 + wk;
        float bv = rpb[(cq - ck + 1267) * 8 + head];
        int rt = tb ? (tk < 4 ? 1 : 2) : 0;
        int rh = hb ? (hk < 4 ? 1 : 2) : 0;
        int rw = wb ? (wk < 4 ? 1 : 2) : 0;
        if (rt * 9 + rh * 3 + rw != labq) bv -= 100.f;
        v = bv * 1.4426950408889634f;
      } else {
        v = -2081.f;  // pad keys: exp2 -> exactly 0
      }
      ob[t * 256] = f2b(v);
    }
  } else {
    int i = (blk - 14144) * 256 + tid;  // < 786432
    const float* src;
    int off;
    if (i < 196608)      { src = qkvw;  off = 0; }
    else if (i < 262144) { src = projw; off = 196608; }
    else if (i < 524288) { src = fc1w;  off = 262144; }
    else                 { src = fc2w;  off = 524288; }
    wts[i] = f2b(src[i - off]);
  }
}

// ---------------- LayerNorm (no gather), for LN2 --------------------------
__global__ __launch_bounds__(256) void ln_k(const float* __restrict__ src,
                                            const float* __restrict__ g,
                                            const float* __restrict__ b,
                                            u16* __restrict__ dst) {
  const int wid = threadIdx.x >> 6, lane = threadIdx.x & 63;
  const int row = blockIdx.x * 4 + wid;
  float4 v = *(const float4*)(src + (size_t)row * 256 + lane * 4);
  float s = v.x + v.y + v.z + v.w;
  float sq = v.x * v.x + v.y * v.y + v.z * v.z + v.w * v.w;
  for (int o = 1; o < 64; o <<= 1) {
    s += __shfl_xor(s, o, 64);
    sq += __shfl_xor(sq, o, 64);
  }
  float mu = s * (1.0f / 256.0f);
  float rstd = rsqrtf(sq * (1.0f / 256.0f) - mu * mu + 1e-5f);
  float4 gg = *(const float4*)(g + lane * 4);
  float4 bb = *(const float4*)(b + lane * 4);
  ushort4 ov;
  ov.x = f2b((v.x - mu) * rstd * gg.x + bb.x);
  ov.y = f2b((v.y - mu) * rstd * gg.y + bb.y);
  ov.z = f2b((v.z - mu) * rstd * gg.z + bb.z);
  ov.w = f2b((v.w - mu) * rstd * gg.w + bb.w);
  *(ushort4*)(dst + (size_t)row * 256 + lane * 4) = ov;
}

// ---------------- MFMA GEMM: C = A(MxK) @ B(NxK)^T -----------------------
// EPI0's s==2 (V) output goes to the PV B-fragment layout
// vfrag[bid][c][half][lane][8] (coalesced epilogue + linear attn staging).
template <int EPI>
__global__ __launch_bounds__(512) void gemm_k(const u16* __restrict__ A,
                                              const u16* __restrict__ Bw,
                                              int K, int tilesN,
                                              const float* __restrict__ bias,
                                              u16* __restrict__ outb,
                                              float* __restrict__ outf,
                                              const float* __restrict__ res,
                                              float qscale) {
  __shared__ __align__(16) u16 As[2][256 * 32];
  __shared__ __align__(16) u16 Bs[2][128 * 32];
  const int tid = threadIdx.x;
  const int swzb = ((int)blockIdx.x & 7) * ((int)gridDim.x >> 3) +
                   ((int)blockIdx.x >> 3);
  const int tm = swzb / tilesN, tn = swzb - tm * tilesN;
  const int wid = tid >> 6, lane = tid & 63;
  const int wm = wid >> 1, wn = wid & 1;
  const int lm = lane & 15, lk = lane >> 4;
  f32x4 acc[4][4] = {};
  const u16* Ap = A + (size_t)tm * 256 * K;
  const u16* Bp = Bw + (size_t)tn * 128 * K;

  const int sA0 = wid * 128;
  const int sB0 = wid * 64;
  const int nt = K >> 5;

#define STAGE(bufi, kk)                                                       \
  {                                                                           \
    int S = sA0 + lane, r = S >> 2, cs = S & 3;                               \
    gload_lds16(Ap + (size_t)r * K + (kk) + ((cs ^ ((r >> 1) & 3)) << 3),     \
                &As[bufi][sA0 * 8]);                                          \
    S = sA0 + 64 + lane; r = S >> 2; cs = S & 3;                              \
    gload_lds16(Ap + (size_t)r * K + (kk) + ((cs ^ ((r >> 1) & 3)) << 3),     \
                &As[bufi][(sA0 + 64) * 8]);                                   \
    S = sB0 + lane; r = S >> 2; cs = S & 3;                                   \
    gload_lds16(Bp + (size_t)r * K + (kk) + ((cs ^ ((r >> 1) & 3)) << 3),     \
                &Bs[bufi][sB0 * 8]);                                          \
  }

  STAGE(0, 0);
  for (int t = 0; t < nt; t++) {
    const int cur = t & 1;
    if (t + 1 < nt) {
      STAGE(cur ^ 1, (t + 1) << 5);
      asm volatile("s_waitcnt vmcnt(3)" ::: "memory");
    } else {
      asm volatile("s_waitcnt vmcnt(0)" ::: "memory");
    }
    asm volatile("s_barrier" ::: "memory");
    __builtin_amdgcn_sched_barrier(0);
    bf16x8 af[4], bfr[4];
#pragma unroll
    for (int f = 0; f < 4; f++) {
      int ra = wm * 64 + f * 16 + lm;
      int rb = wn * 64 + f * 16 + lm;
      af[f] = *(const bf16x8*)((const char*)&As[cur][0] + ra * 64 +
                               ((lk ^ ((ra >> 1) & 3)) << 4));
      bfr[f] = *(const bf16x8*)((const char*)&Bs[cur][0] + rb * 64 +
                                ((lk ^ ((rb >> 1) & 3)) << 4));
    }
#pragma unroll
    for (int fm = 0; fm < 4; fm++)
#pragma unroll
      for (int fn = 0; fn < 4; fn++)
        acc[fm][fn] = __builtin_amdgcn_mfma_f32_16x16x32_bf16(
            af[fm], bfr[fn], acc[fm][fn], 0, 0, 0);
    asm volatile("s_barrier" ::: "memory");
  }
#undef STAGE

  const int rbase = tm * 256 + wm * 64, cbase = tn * 128 + wn * 64;
#pragma unroll
  for (int fm = 0; fm < 4; fm++) {
#pragma unroll
    for (int fn = 0; fn < 4; fn++) {
      const int col = cbase + fn * 16 + lm;
#pragma unroll
      for (int r = 0; r < 4; r++) {
        const int row = rbase + fm * 16 + lk * 4 + r;
        float v = acc[fm][fn][r] + bias[col];
        if (EPI == 0) {
          int s = col >> 8, rem = col & 255, head = rem >> 5, d = rem & 31;
          int widx = row / 392, n = row - widx * 392;
          size_t o;
          if (s == 2) {
            int c = n >> 5, gg2 = (n >> 3) & 3, e = n & 7;
            int lm2 = d & 15, half = d >> 4;
            o = 25690112u + (size_t)(widx * 8 + head) * 13312 +
                (size_t)(((c * 2 + half) * 64) + gg2 * 16 + lm2) * 8 + e;
          } else {
            if (s == 0) v *= qscale;
            o = (size_t)s * 12845056u +
                (((size_t)(widx * 8 + head)) * 392 + n) * 32 + d;
          }
          outb[o] = f2b(v);
        } else if (EPI == 1) {
          int widx = row / 392, n = row - widx * 392;
          int wt = widx >> 6, wh = (widx >> 3) & 7, ww = widx & 7;
          int ti = n / 49, rem2 = n - ti * 49, hi = rem2 / 7, wi = rem2 - hi * 7;
          int t = (wt * 8 + ti + 4) & 15;
          int h = wh * 7 + hi + 3; if (h >= 56) h -= 56;
          int w = ww * 7 + wi + 3; if (w >= 56) w -= 56;
          size_t dr = ((size_t)(t * 56 + h)) * 56 + w;
          outf[dr * 256 + col] = res[dr * 256 + col] + v;
        } else if (EPI == 2) {
          float gv = 0.5f * v * (1.0f + erff(v * 0.70710678f));
          outb[(size_t)row * 1024 + col] = f2b(gv);
        } else {
          outf[(size_t)row * 256 + col] = res[(size_t)row * 256 + col] + v;
        }
      }
    }
  }
}

// ---------------- MFMA windowed attention (round-18, proven 292us config) -
// LDS 59904 B: K [392][64B swz] @0 + Vfrag (26624 B, linear copy of the
// pre-fragmented global V) @25088 + Pq dbuf @51712. PV's V read is a
// contiguous 1KB wave read (c*2048 + lane*16) -> conflict-free.
__global__ __launch_bounds__(256) void attn_k(const u16* __restrict__ qg,
                                              const u16* __restrict__ kg,
                                              const u16* __restrict__ vfg,
                                              const u16* __restrict__ biasB,
                                              u16* __restrict__ attno) {
  __shared__ __align__(16) char lds[59904];
  const int bid = blockIdx.x;  // widx*8 + head
  const int widx = bid >> 3;
  const int tid = threadIdx.x;
  const size_t base = (size_t)bid * 12544;
  const int tb = (widx >> 6) & 1;
  const int hb = (((widx >> 3) & 7) == 7) ? 1 : 0;
  const int wb = ((widx & 7) == 7) ? 1 : 0;
  const int sl = (tb * 4 + hb * 2 + wb) * 8 + (bid & 7);
  const int VOFF = 25088;
  const int POFF = 51712;

#pragma unroll
  for (int i = 0; i < 6; i++) {
    int s = i * 256 + tid, r = s >> 2, cs = s & 3;
    gload_lds16(kg + base + r * 32 + ((cs ^ ((r >> 1) & 3)) << 3),
                (u16*)(lds + (size_t)(i * 256 + (tid & ~63)) * 16));
  }
  if (tid < 32) {
    int s = 1536 + tid, r = s >> 2, cs = s & 3;
    gload_lds16(kg + base + r * 32 + ((cs ^ ((r >> 1) & 3)) << 3),
                (u16*)(lds + (size_t)1536 * 16));
  }
  {
    const u16* vsrc = vfg + (size_t)bid * 13312;
#pragma unroll
    for (int i = 0; i < 6; i++) {
      int s = i * 256 + tid;
      gload_lds16(vsrc + (size_t)s * 8,
                  (u16*)(lds + VOFF + (size_t)(i * 256 + (tid & ~63)) * 16));
    }
    if (tid < 128) {
      int s = 1536 + tid;
      gload_lds16(vsrc + (size_t)s * 8,
                  (u16*)(lds + VOFF + (size_t)(1536 + (tid & ~63)) * 16));
    }
  }
  __syncthreads();

  const int w = tid >> 6, lane = tid & 63;
  const int g = lane >> 4, lm = lane & 15;
  const int kswz = ((lm >> 1) & 3);
  char* PqW = lds + POFF + w * 2048 + lm * 128;
  const int swz = (lm & 7) << 4;
  const char* vlds = lds + VOFF + lane * 16;

  for (int qt = w; qt < 25; qt += 4) {
    const int q = qt * 16 + lm;
    const int qr = q < 391 ? q : 391;
    bf16x8 qf = *(const bf16x8*)(qg + base + (size_t)qr * 32 + g * 8);
    const u16* bp = biasB + ((size_t)(sl * 25 + qt) * 25) * 256 + lm * 16 + 4 * g;
    f32x4 st[25];
#pragma unroll
    for (int t = 0; t < 25; t++) {
      ushort4 bb = *(const ushort4*)(bp + t * 256);
      f32x4 bacc = {b2f(bb.x), b2f(bb.y), b2f(bb.z), b2f(bb.w)};
      int kr = (t < 24) ? (16 * t + lm) : (384 + (lm & 7));
      bf16x8 kf = *(const bf16x8*)(lds + kr * 64 + ((g ^ kswz) << 4));
      st[t] = __builtin_amdgcn_mfma_f32_16x16x32_bf16(kf, qf, bacc, 0, 0, 0);
    }
    float m = -3e38f;
#pragma unroll
    for (int t = 0; t < 25; t++)
      m = fmaxf(m, fmaxf(fmaxf(st[t][0], st[t][1]), fmaxf(st[t][2], st[t][3])));
    m = fmaxf(m, __shfl_xor(m, 16, 64));
    m = fmaxf(m, __shfl_xor(m, 32, 64));

    float sum = 0.f;
    f32x4 oa0 = {0.f, 0.f, 0.f, 0.f}, oa1 = {0.f, 0.f, 0.f, 0.f};
#pragma unroll
    for (int c = 0; c < 13; c++) {
      const int p64 = (c & 1) << 6;
      {
        int t = 2 * c;
        float e0 = vexp2(st[t][0] - m), e1 = vexp2(st[t][1] - m);
        float e2 = vexp2(st[t][2] - m), e3 = vexp2(st[t][3] - m);
        sum += (e0 + e1) + (e2 + e3);
        uint2 pp;
        pp.x = cvtpk(e0, e1);
        pp.y = cvtpk(e2, e3);
        *(uint2*)(PqW + ((p64 + 8 * g) ^ swz)) = pp;
      }
      {
        uint2 pp;
        if (c < 12) {
          int t = 2 * c + 1;
          float e0 = vexp2(st[t][0] - m), e1 = vexp2(st[t][1] - m);
          float e2 = vexp2(st[t][2] - m), e3 = vexp2(st[t][3] - m);
          sum += (e0 + e1) + (e2 + e3);
          pp.x = cvtpk(e0, e1);
          pp.y = cvtpk(e2, e3);
        } else {
          pp.x = 0u; pp.y = 0u;
        }
        *(uint2*)(PqW + ((p64 + 32 + 8 * g) ^ swz)) = pp;
      }
      bf16x8 pf = *(const bf16x8*)(PqW + ((p64 + 16 * g) ^ swz));
      const char* vp = vlds + c * 2048;
      bf16x8 v0 = *(const bf16x8*)vp;           // half 0: d = lm
      bf16x8 v1 = *(const bf16x8*)(vp + 1024);  // half 1: d = 16+lm
      oa0 = __builtin_amdgcn_mfma_f32_16x16x32_bf16(pf, v0, oa0, 0, 0, 0);
      oa1 = __builtin_amdgcn_mfma_f32_16x16x32_bf16(pf, v1, oa1, 0, 0, 0);
    }
    sum += __shfl_xor(sum, 16, 64);
    sum += __shfl_xor(sum, 32, 64);
    const float inv = 1.f / sum;
#pragma unroll
    for (int r = 0; r < 4; r++) {
      int qq = qt * 16 + 4 * g + r;
      if (qq < 392) {
        u16* op = attno + ((size_t)(widx * 392 + qq)) * 256 + (bid & 7) * 32;
        op[lm] = f2b(oa0[r] * inv);
        op[16 + lm] = f2b(oa1[r] * inv);
      }
    }
  }
}

extern "C" void kernel_launch(void* const* d_in, const int* in_sizes, int n_in,
                              void* d_out, int out_size, void* d_ws,
                              size_t ws_size, hipStream_t stream) {
  const float* x     = (const float*)d_in[0];
  const float* n1g   = (const float*)d_in[1];
  const float* n1b   = (const float*)d_in[2];
  const float* qkvw  = (const float*)d_in[3];
  const float* qkvb  = (const float*)d_in[4];
  const float* rpb   = (const float*)d_in[5];
  const float* projw = (const float*)d_in[6];
  const float* projb = (const float*)d_in[7];
  const float* n2g   = (const float*)d_in[8];
  const float* n2b   = (const float*)d_in[9];
  const float* fc1w  = (const float*)d_in[10];
  const float* fc1b  = (const float*)d_in[11];
  const float* fc2w  = (const float*)d_in[12];
  const float* fc2b  = (const float*)d_in[13];

  // Workspace (NEED = 130,547,712 B), lifetime-aliased (round-18 layout):
  //  [0, 25.69M)            xw -> attno -> h2
  //  [25.69M, 77.07M)       q,k           -> hid (low)
  //  [77.07M, 104.33M)      vfrag (27.3M) -> hid (high)
  //  [104.33M, 124.81M)     biasB         -> hid (high)
  //  hid = [25.69M, 128.45M)
  //  [128.97M, 130.55M)     bf16 weights (wq|wp|w1|w2 contiguous)
  // xres (fp32 residual) lives in d_out.
  const size_t NEED = 130547712;
  if (ws_size < NEED) return;

  char* ws = (char*)d_ws;
  u16* xw      = (u16*)(ws + 0LL);
  u16* qb      = (u16*)(ws + 25690112LL);
  u16* attno   = (u16*)(ws + 0LL);
  u16* h2      = (u16*)(ws + 0LL);
  u16* hid     = (u16*)(ws + 25690112LL);
  u16* biasB   = (u16*)(ws + 104333312LL);
  u16* wq      = (u16*)(ws + 128974848LL);
  u16* wp      = (u16*)(ws + 129368064LL);
  u16* w1      = (u16*)(ws + 129499136LL);
  u16* w2      = (u16*)(ws + 130023424LL);
  float* xres  = (float*)d_out;

  pre_k<<<17216, 256, 0, stream>>>(x, n1g, n1b, qkvw, projw, fc1w, fc2w, rpb,
                                   xw, wq, biasB);
  gemm_k<0><<<196 * 6, 512, 0, stream>>>(
      xw, wq, 256, 6, qkvb, qb, nullptr, nullptr,
      0.17677669529663687f * 1.4426950408889634f);
  attn_k<<<1024, 256, 0, stream>>>(qb, qb + 12845056, qb + 2 * 12845056, biasB,
                                   attno);
  gemm_k<1><<<196 * 2, 512, 0, stream>>>(attno, wp, 256, 2, projb, nullptr,
                                         xres, x, 0.f);
  ln_k<<<12544, 256, 0, stream>>>(xres, n2g, n2b, h2);
  gemm_k<2><<<196 * 8, 512, 0, stream>>>(h2, w1, 256, 8, fc1b, hid, nullptr,
                                         nullptr, 0.f);
  gemm_k<3><<<196 * 2, 512, 0, stream>>>(hid, w2, 1024, 2, fc2b, nullptr,
                                         (float*)d_out, xres, 0.f);
}